// Round 1
// baseline (243.471 us; speedup 1.0000x reference)
//
#include <hip/hip_runtime.h>
#include <stdint.h>

#define S_LEN 1024
#define DDIM  512
#define NBATCH 16

typedef __attribute__((ext_vector_type(8))) short bf16x8;
typedef __attribute__((ext_vector_type(4))) float f32x4;

__device__ __forceinline__ unsigned short f2bf(float x) {
  union { float f; uint32_t u; } v; v.f = x;
  return (unsigned short)((v.u + 0x7fffu + ((v.u >> 16) & 1u)) >> 16);
}
__device__ __forceinline__ float bf2f(unsigned short h) {
  union { float f; uint32_t u; } v; v.u = ((uint32_t)h) << 16;
  return v.f;
}

__device__ __forceinline__ void gload16(const void* g, void* l) {
  __builtin_amdgcn_global_load_lds(
      (const __attribute__((address_space(1))) void*)g,
      (__attribute__((address_space(3))) void*)l, 16, 0, 0);
}

// ---------------------------------------------------------------------------
// K1: per-row prep: sj[row] = P[row,:]·wb ; Pbf = bf16(P) ; Qbf = bf16(P*wc)
// one wave per row, 4 rows per block
__global__ __launch_bounds__(256) void prep_rows(
    const float* __restrict__ P, const float* __restrict__ w_atten,
    unsigned short* __restrict__ Pbf, unsigned short* __restrict__ Qbf,
    float* __restrict__ sj) {
  int wave = threadIdx.x >> 6, lane = threadIdx.x & 63;
  int row = blockIdx.x * 4 + wave;            // 0..16383
  const float* prow = P + (size_t)row * DDIM;
  float s = 0.f;
#pragma unroll
  for (int h = 0; h < 2; ++h) {
    int d = h * 256 + lane * 4;
    float4 p  = *(const float4*)(prow + d);
    float4 wb = *(const float4*)(w_atten + DDIM + d);
    float4 wc = *(const float4*)(w_atten + 2 * DDIM + d);
    s += p.x * wb.x + p.y * wb.y + p.z * wb.z + p.w * wb.w;
    ushort4 pb, qb;
    pb.x = f2bf(p.x); pb.y = f2bf(p.y); pb.z = f2bf(p.z); pb.w = f2bf(p.w);
    qb.x = f2bf(p.x * wc.x); qb.y = f2bf(p.y * wc.y);
    qb.z = f2bf(p.z * wc.z); qb.w = f2bf(p.w * wc.w);
    *(ushort4*)(Pbf + (size_t)row * DDIM + d) = pb;
    *(ushort4*)(Qbf + (size_t)row * DDIM + d) = qb;
  }
#pragma unroll
  for (int o = 32; o; o >>= 1) s += __shfl_xor(s, o);
  if (lane == 0) sj[row] = s;
}

// ---------------------------------------------------------------------------
// K2: tiled transpose fp32[R][C] -> bf16[C][R]   (64x64 tiles)
__global__ __launch_bounds__(256) void transpose_f2b(
    const float* __restrict__ in, unsigned short* __restrict__ out,
    int R, int C, long inStride, long outStride) {
  __shared__ unsigned short T[64][65];
  in  += (size_t)blockIdx.z * inStride;
  out += (size_t)blockIdx.z * outStride;
  int c0 = blockIdx.x * 64, r0 = blockIdx.y * 64;
  int tx = threadIdx.x & 63, ty = threadIdx.x >> 6;
#pragma unroll
  for (int rr = 0; rr < 16; ++rr) {
    int rl = ty * 16 + rr;
    T[rl][tx] = f2bf(in[(size_t)(r0 + rl) * C + c0 + tx]);
  }
  __syncthreads();
#pragma unroll
  for (int rr = 0; rr < 16; ++rr) {
    int cl = ty * 16 + rr;
    out[(size_t)(c0 + cl) * R + r0 + tx] = T[tx][cl];
  }
}

// ---------------------------------------------------------------------------
// Core bf16 NT GEMM: C[M][N] = A[M][K(lda)] * Bt[N][K]^T  (both k-major)
// 128x128 tile, BK=32, 4 waves (2x2), 16x16x32 MFMA, global_load_lds staging.
// A2/Ksplit: rows of A switch to A2 for k >= Ksplit (concat along K).
// EPI: 0 = plain bf16 store, 1 = +bias[col], 2 = tanh(+bias), 3 = sigmoid(+bias)
template<int EPI>
__global__ __launch_bounds__(256) void gemm_nt(
    const unsigned short* __restrict__ A,
    const unsigned short* __restrict__ A2,
    const unsigned short* __restrict__ Bt,
    unsigned short* __restrict__ C,
    const float* __restrict__ bias,
    int N, int K, int lda, int Ksplit,
    long sAb, long sBb, long sCb, long sBiasb) {
  __shared__ __align__(16) unsigned short lA[128 * 32];
  __shared__ __align__(16) unsigned short lB[128 * 32];
  const int t = threadIdx.x;
  const int lane = t & 63;
  const int wave = t >> 6;
  const int z = blockIdx.z;
  A  += (size_t)z * sAb;
  if (A2) A2 += (size_t)z * sAb;
  Bt += (size_t)z * sBb;
  C  += (size_t)z * sCb;
  if (bias) bias += (size_t)z * sBiasb;
  const int bm = blockIdx.y * 128, bn = blockIdx.x * 128;

  f32x4 acc[4][4];
#pragma unroll
  for (int m = 0; m < 4; ++m)
#pragma unroll
    for (int n = 0; n < 4; ++n) acc[m][n] = {0.f, 0.f, 0.f, 0.f};

  const int wr = wave >> 1, wc = wave & 1;
  const int frow = lane & 15;
  const int fk = (lane >> 4) * 8;       // element offset into BK=32
  const int srow = t >> 2;              // staging row (plus r2*64)
  const int skc = (t & 3) * 8;          // staging k chunk (8 elems = 16B)

  for (int k0 = 0; k0 < K; k0 += 32) {
    const unsigned short* Asrc = A;
    int ka = k0;
    if (A2 != nullptr && k0 >= Ksplit) { Asrc = A2; ka = k0 - Ksplit; }
#pragma unroll
    for (int r2 = 0; r2 < 2; ++r2) {
      int row = r2 * 64 + srow;
      gload16(Asrc + (size_t)(bm + row) * lda + ka + skc,
              lA + (size_t)(r2 * 256 + (t & 192)) * 8);
    }
#pragma unroll
    for (int r2 = 0; r2 < 2; ++r2) {
      int row = r2 * 64 + srow;
      gload16(Bt + (size_t)(bn + row) * K + k0 + skc,
              lB + (size_t)(r2 * 256 + (t & 192)) * 8);
    }
    __syncthreads();
    bf16x8 af[4], bfr[4];
#pragma unroll
    for (int m = 0; m < 4; ++m)
      af[m] = *(const bf16x8*)(lA + (wr * 64 + m * 16 + frow) * 32 + fk);
#pragma unroll
    for (int n = 0; n < 4; ++n)
      bfr[n] = *(const bf16x8*)(lB + (wc * 64 + n * 16 + frow) * 32 + fk);
#pragma unroll
    for (int m = 0; m < 4; ++m)
#pragma unroll
      for (int n = 0; n < 4; ++n)
        acc[m][n] = __builtin_amdgcn_mfma_f32_16x16x32_bf16(af[m], bfr[n], acc[m][n], 0, 0, 0);
    __syncthreads();
  }
  // epilogue: D layout col = lane&15, row = (lane>>4)*4 + i
#pragma unroll
  for (int m = 0; m < 4; ++m) {
    int row0 = bm + wr * 64 + m * 16 + (lane >> 4) * 4;
#pragma unroll
    for (int n = 0; n < 4; ++n) {
      int col = bn + wc * 64 + n * 16 + (lane & 15);
      float bc = (EPI >= 1) ? bias[col] : 0.f;
#pragma unroll
      for (int i = 0; i < 4; ++i) {
        float v = acc[m][n][i];
        if (EPI == 1) v += bc;
        if (EPI == 2) v = tanhf(v + bc);
        if (EPI == 3) v = 1.f / (1.f + __expf(-(v + bc)));
        C[(size_t)(row0 + i) * N + col] = f2bf(v);
      }
    }
  }
}

// ---------------------------------------------------------------------------
// K5: in-place row softmax over 1024 bf16 scores, one block per row
__global__ __launch_bounds__(256) void softmax_rows(unsigned short* __restrict__ Sb) {
  __shared__ float red[8];
  unsigned short* p = Sb + (size_t)blockIdx.x * S_LEN;
  int t = threadIdx.x, wave = t >> 6, lane = t & 63;
  ushort4 u = *(ushort4*)(p + t * 4);
  float v0 = bf2f(u.x), v1 = bf2f(u.y), v2 = bf2f(u.z), v3 = bf2f(u.w);
  float mx = fmaxf(fmaxf(v0, v1), fmaxf(v2, v3));
#pragma unroll
  for (int o = 32; o; o >>= 1) mx = fmaxf(mx, __shfl_xor(mx, o));
  if (lane == 0) red[wave] = mx;
  __syncthreads();
  mx = fmaxf(fmaxf(red[0], red[1]), fmaxf(red[2], red[3]));
  float e0 = __expf(v0 - mx), e1 = __expf(v1 - mx);
  float e2 = __expf(v2 - mx), e3 = __expf(v3 - mx);
  float ss = e0 + e1 + e2 + e3;
#pragma unroll
  for (int o = 32; o; o >>= 1) ss += __shfl_xor(ss, o);
  if (lane == 0) red[4 + wave] = ss;
  __syncthreads();
  float inv = 1.f / (red[4] + red[5] + red[6] + red[7]);
  u.x = f2bf(e0 * inv); u.y = f2bf(e1 * inv);
  u.z = f2bf(e2 * inv); u.w = f2bf(e3 * inv);
  *(ushort4*)(p + t * 4) = u;
}

// ---------------------------------------------------------------------------
// K8: out = r*P + f*z  (r,f,z bf16; P, out fp32)
__global__ __launch_bounds__(256) void final_out(
    const float* __restrict__ P, const unsigned short* __restrict__ zb,
    const unsigned short* __restrict__ rb, const unsigned short* __restrict__ fb,
    float* __restrict__ out) {
  size_t i = ((size_t)blockIdx.x * 256 + threadIdx.x) * 4;
  float4 p = *(const float4*)(P + i);
  ushort4 z4 = *(const ushort4*)(zb + i);
  ushort4 r4 = *(const ushort4*)(rb + i);
  ushort4 f4 = *(const ushort4*)(fb + i);
  float4 o;
  o.x = bf2f(r4.x) * p.x + bf2f(f4.x) * bf2f(z4.x);
  o.y = bf2f(r4.y) * p.y + bf2f(f4.y) * bf2f(z4.y);
  o.z = bf2f(r4.z) * p.z + bf2f(f4.z) * bf2f(z4.z);
  o.w = bf2f(r4.w) * p.w + bf2f(f4.w) * bf2f(z4.w);
  *(float4*)(out + i) = o;
}

// ---------------------------------------------------------------------------
extern "C" void kernel_launch(void* const* d_in, const int* in_sizes, int n_in,
                              void* d_out, int out_size, void* d_ws, size_t ws_size,
                              hipStream_t stream) {
  const float* P  = (const float*)d_in[0];
  const float* wa = (const float*)d_in[1];
  const float* w1 = (const float*)d_in[2];
  const float* w2 = (const float*)d_in[3];
  const float* w3 = (const float*)d_in[4];
  const float* b1 = (const float*)d_in[5];
  const float* b2 = (const float*)d_in[6];
  const float* b3 = (const float*)d_in[7];
  float* out = (float*)d_out;
  char* ws = (char*)d_ws;
  const size_t MB = 1024 * 1024;

  unsigned short* Pbf  = (unsigned short*)(ws + 0);        // 16 MB, live to end of MLP
  unsigned short* PT   = (unsigned short*)(ws + 16 * MB);  // 16 MB, dead after PV gemm
  unsigned short* Qbf  = (unsigned short*)(ws + 32 * MB);  // 16 MB, dead after scores
  unsigned short* Sbuf = (unsigned short*)(ws + 48 * MB);  // 32 MB, dead after PV gemm
  unsigned short* attn = (unsigned short*)(ws + 80 * MB);  // 16 MB
  unsigned short* Wt   = (unsigned short*)(ws + 96 * MB);  // 3 MB
  float*          sj   = (float*)(ws + 99 * MB);           // 64 KB
  unsigned short* zb   = (unsigned short*)(ws + 16 * MB);  // reuse PT
  unsigned short* rb   = (unsigned short*)(ws + 32 * MB);  // reuse Qbf
  unsigned short* fb   = (unsigned short*)(ws + 48 * MB);  // reuse Sbuf

  const long SD = (long)S_LEN * DDIM;        // 1024*512
  const long SS = (long)S_LEN * S_LEN;       // 1024*1024

  prep_rows<<<4096, 256, 0, stream>>>(P, wa, Pbf, Qbf, sj);
  transpose_f2b<<<dim3(8, 16, NBATCH), 256, 0, stream>>>(P, PT, S_LEN, DDIM, SD, SD);
  transpose_f2b<<<dim3(8, 16, 1), 256, 0, stream>>>(w1, Wt,          1024, 512, 0, 0);
  transpose_f2b<<<dim3(8, 16, 1), 256, 0, stream>>>(w2, Wt + SD,     1024, 512, 0, 0);
  transpose_f2b<<<dim3(8, 16, 1), 256, 0, stream>>>(w3, Wt + 2 * SD, 1024, 512, 0, 0);

  // scores: S[b] = Qbf[b] @ Pbf[b]^T + sj[b][col]   (M=N=1024, K=512)
  gemm_nt<1><<<dim3(8, 8, NBATCH), 256, 0, stream>>>(
      Qbf, nullptr, Pbf, Sbuf, sj, 1024, 512, 512, 0, SD, SD, SS, S_LEN);
  softmax_rows<<<16384, 256, 0, stream>>>(Sbuf);
  // attn[b] = SA[b] @ PT[b]^T   (M=1024, N=512, K=1024)
  gemm_nt<0><<<dim3(4, 8, NBATCH), 256, 0, stream>>>(
      Sbuf, nullptr, PT, attn, nullptr, 512, 1024, 1024, 0, SS, SD, SD, 0);
  // MLP: Pc = [Pbf | attn] (K=1024, split 512), N=512, M=16384
  gemm_nt<2><<<dim3(4, 128, 1), 256, 0, stream>>>(
      Pbf, attn, Wt,          zb, b1, 512, 1024, 512, 512, 0, 0, 0, 0);
  gemm_nt<3><<<dim3(4, 128, 1), 256, 0, stream>>>(
      Pbf, attn, Wt + SD,     rb, b2, 512, 1024, 512, 512, 0, 0, 0, 0);
  gemm_nt<3><<<dim3(4, 128, 1), 256, 0, stream>>>(
      Pbf, attn, Wt + 2 * SD, fb, b3, 512, 1024, 512, 512, 0, 0, 0, 0);

  final_out<<<8192, 256, 0, stream>>>(P, zb, rb, fb, out);
}

// Round 2
// 213.323 us; speedup vs baseline: 1.1413x; 1.1413x over previous
//
#include <hip/hip_runtime.h>
#include <stdint.h>

#define S_LEN 1024
#define DDIM  512
#define NBATCH 16

typedef __attribute__((ext_vector_type(8))) short bf16x8;
typedef __attribute__((ext_vector_type(4))) float f32x4;

__device__ __forceinline__ unsigned short f2bf(float x) {
  union { float f; uint32_t u; } v; v.f = x;
  return (unsigned short)((v.u + 0x7fffu + ((v.u >> 16) & 1u)) >> 16);
}
__device__ __forceinline__ float bf2f(unsigned short h) {
  union { float f; uint32_t u; } v; v.u = ((uint32_t)h) << 16;
  return v.f;
}

__device__ __forceinline__ void gload16(const void* g, void* l) {
  __builtin_amdgcn_global_load_lds(
      (const __attribute__((address_space(1))) void*)g,
      (__attribute__((address_space(3))) void*)l, 16, 0, 0);
}

// ---------------------------------------------------------------------------
// K1: per-row prep: sj[row] = P[row,:]·wb ; Pbf = bf16(P) ; Qbf = bf16(P*wc)
__global__ __launch_bounds__(256) void prep_rows(
    const float* __restrict__ P, const float* __restrict__ w_atten,
    unsigned short* __restrict__ Pbf, unsigned short* __restrict__ Qbf,
    float* __restrict__ sj) {
  int wave = threadIdx.x >> 6, lane = threadIdx.x & 63;
  int row = blockIdx.x * 4 + wave;
  const float* prow = P + (size_t)row * DDIM;
  float s = 0.f;
#pragma unroll
  for (int h = 0; h < 2; ++h) {
    int d = h * 256 + lane * 4;
    float4 p  = *(const float4*)(prow + d);
    float4 wb = *(const float4*)(w_atten + DDIM + d);
    float4 wc = *(const float4*)(w_atten + 2 * DDIM + d);
    s += p.x * wb.x + p.y * wb.y + p.z * wb.z + p.w * wb.w;
    ushort4 pb, qb;
    pb.x = f2bf(p.x); pb.y = f2bf(p.y); pb.z = f2bf(p.z); pb.w = f2bf(p.w);
    qb.x = f2bf(p.x * wc.x); qb.y = f2bf(p.y * wc.y);
    qb.z = f2bf(p.z * wc.z); qb.w = f2bf(p.w * wc.w);
    *(ushort4*)(Pbf + (size_t)row * DDIM + d) = pb;
    *(ushort4*)(Qbf + (size_t)row * DDIM + d) = qb;
  }
#pragma unroll
  for (int o = 32; o; o >>= 1) s += __shfl_xor(s, o);
  if (lane == 0) sj[row] = s;
}

// ---------------------------------------------------------------------------
// K2: tiled transpose fp32[R][C] -> bf16[C][R]   (64x64 tiles)
__global__ __launch_bounds__(256) void transpose_f2b(
    const float* __restrict__ in, unsigned short* __restrict__ out,
    int R, int C, long inStride, long outStride) {
  __shared__ unsigned short T[64][65];
  in  += (size_t)blockIdx.z * inStride;
  out += (size_t)blockIdx.z * outStride;
  int c0 = blockIdx.x * 64, r0 = blockIdx.y * 64;
  int tx = threadIdx.x & 63, ty = threadIdx.x >> 6;
#pragma unroll
  for (int rr = 0; rr < 16; ++rr) {
    int rl = ty * 16 + rr;
    T[rl][tx] = f2bf(in[(size_t)(r0 + rl) * C + c0 + tx]);
  }
  __syncthreads();
#pragma unroll
  for (int rr = 0; rr < 16; ++rr) {
    int cl = ty * 16 + rr;
    out[(size_t)(c0 + cl) * R + r0 + tx] = T[tx][cl];
  }
}

// ---------------------------------------------------------------------------
// Core bf16 NT GEMM, 2-phase double-buffered prefetch (T3-minimum).
// C[M][N] = A[M][K(lda)] * Bt[N][K]^T  (both k-major)
// 128x128 tile, BK=32, 4 waves (2x2), 16x16x32 MFMA, global_load_lds staging.
// A2/Ksplit: rows of A switch to A2 for k >= Ksplit (concat along K).
// EPI: 0 = plain bf16 store, 1 = +bias[col] (scores),
//      4 = fused MLP: seg = col>>9; +bias_seg[col&511]; seg0 tanh else sigmoid
template<int EPI>
__global__ __launch_bounds__(256) void gemm_nt(
    const unsigned short* __restrict__ A,
    const unsigned short* __restrict__ A2,
    const unsigned short* __restrict__ Bt,
    unsigned short* __restrict__ C,
    const float* __restrict__ bias,
    const float* __restrict__ bias2,
    const float* __restrict__ bias3,
    int N, int K, int lda, int Ksplit,
    long sAb, long sBb, long sCb, long sBiasb) {
  __shared__ __align__(16) unsigned short lA[2][128 * 32];
  __shared__ __align__(16) unsigned short lB[2][128 * 32];
  const int t = threadIdx.x;
  const int lane = t & 63;
  const int wave = t >> 6;
  const int z = blockIdx.z;
  A  += (size_t)z * sAb;
  if (A2) A2 += (size_t)z * sAb;
  Bt += (size_t)z * sBb;
  C  += (size_t)z * sCb;
  if (bias) bias += (size_t)z * sBiasb;
  const int bm = blockIdx.y * 128, bn = blockIdx.x * 128;

  f32x4 acc[4][4];
#pragma unroll
  for (int m = 0; m < 4; ++m)
#pragma unroll
    for (int n = 0; n < 4; ++n) acc[m][n] = {0.f, 0.f, 0.f, 0.f};

  const int wr = wave >> 1, wc = wave & 1;
  const int frow = lane & 15;
  const int fk = (lane >> 4) * 8;       // element offset into BK=32
  const int srow = t >> 2;              // staging row within 64-row group
  const int skc = (t & 3) * 8;          // staging k chunk (8 elems = 16B)
  const int lbase = (t & 192) * 8;      // wave-uniform LDS base (shorts)

  auto stage = [&](int buf, int k0) {
    const unsigned short* Asrc = A;
    int ka = k0;
    if (A2 != nullptr && k0 >= Ksplit) { Asrc = A2; ka = k0 - Ksplit; }
#pragma unroll
    for (int r2 = 0; r2 < 2; ++r2)
      gload16(Asrc + (size_t)(bm + r2 * 64 + srow) * lda + ka + skc,
              lA[buf] + r2 * 2048 + lbase);
#pragma unroll
    for (int r2 = 0; r2 < 2; ++r2)
      gload16(Bt + (size_t)(bn + r2 * 64 + srow) * K + k0 + skc,
              lB[buf] + r2 * 2048 + lbase);
  };

  stage(0, 0);
  __syncthreads();
  int cur = 0;
  for (int k0 = 0; k0 < K; k0 += 32) {
    if (k0 + 32 < K) stage(cur ^ 1, k0 + 32);   // prefetch next tile
    bf16x8 af[4], bfr[4];
#pragma unroll
    for (int m = 0; m < 4; ++m)
      af[m] = *(const bf16x8*)(lA[cur] + (wr * 64 + m * 16 + frow) * 32 + fk);
#pragma unroll
    for (int n = 0; n < 4; ++n)
      bfr[n] = *(const bf16x8*)(lB[cur] + (wc * 64 + n * 16 + frow) * 32 + fk);
#pragma unroll
    for (int m = 0; m < 4; ++m)
#pragma unroll
      for (int n = 0; n < 4; ++n)
        acc[m][n] = __builtin_amdgcn_mfma_f32_16x16x32_bf16(af[m], bfr[n], acc[m][n], 0, 0, 0);
    __syncthreads();   // drains prefetch vmcnt + protects buffer swap
    cur ^= 1;
  }

  // epilogue: D layout col = lane&15, row = (lane>>4)*4 + i
  const int seg = bn >> 9;   // block-uniform for EPI==4 (bn%512 in {0,128,256,384})
  const float* bp = bias;
  if (EPI == 4) bp = (seg == 0) ? bias : ((seg == 1) ? bias2 : bias3);
#pragma unroll
  for (int m = 0; m < 4; ++m) {
    int row0 = bm + wr * 64 + m * 16 + (lane >> 4) * 4;
#pragma unroll
    for (int n = 0; n < 4; ++n) {
      int col = bn + wc * 64 + n * 16 + (lane & 15);
      float bc = (EPI >= 1) ? bp[(EPI == 4) ? (col & 511) : col] : 0.f;
#pragma unroll
      for (int i = 0; i < 4; ++i) {
        float v = acc[m][n][i];
        if (EPI == 1) v += bc;
        if (EPI == 4) {
          v += bc;
          v = (seg == 0) ? tanhf(v) : 1.f / (1.f + __expf(-v));
        }
        C[(size_t)(row0 + i) * N + col] = f2bf(v);
      }
    }
  }
}

// ---------------------------------------------------------------------------
// K5: in-place row softmax over 1024 bf16 scores, one block per row
__global__ __launch_bounds__(256) void softmax_rows(unsigned short* __restrict__ Sb) {
  __shared__ float red[8];
  unsigned short* p = Sb + (size_t)blockIdx.x * S_LEN;
  int t = threadIdx.x, wave = t >> 6, lane = t & 63;
  ushort4 u = *(ushort4*)(p + t * 4);
  float v0 = bf2f(u.x), v1 = bf2f(u.y), v2 = bf2f(u.z), v3 = bf2f(u.w);
  float mx = fmaxf(fmaxf(v0, v1), fmaxf(v2, v3));
#pragma unroll
  for (int o = 32; o; o >>= 1) mx = fmaxf(mx, __shfl_xor(mx, o));
  if (lane == 0) red[wave] = mx;
  __syncthreads();
  mx = fmaxf(fmaxf(red[0], red[1]), fmaxf(red[2], red[3]));
  float e0 = __expf(v0 - mx), e1 = __expf(v1 - mx);
  float e2 = __expf(v2 - mx), e3 = __expf(v3 - mx);
  float ss = e0 + e1 + e2 + e3;
#pragma unroll
  for (int o = 32; o; o >>= 1) ss += __shfl_xor(ss, o);
  if (lane == 0) red[4 + wave] = ss;
  __syncthreads();
  float inv = 1.f / (red[4] + red[5] + red[6] + red[7]);
  u.x = f2bf(e0 * inv); u.y = f2bf(e1 * inv);
  u.z = f2bf(e2 * inv); u.w = f2bf(e3 * inv);
  *(ushort4*)(p + t * 4) = u;
}

// ---------------------------------------------------------------------------
// K8: out = r*P + f*z  reading fused MLP output Cm[16384][1536] = [z|r|f]
__global__ __launch_bounds__(256) void final_out(
    const float* __restrict__ P, const unsigned short* __restrict__ Cm,
    float* __restrict__ out) {
  size_t i = ((size_t)blockIdx.x * 256 + threadIdx.x) * 4;  // elem idx in [16384][512]
  size_t row = i >> 9;
  int col = (int)(i & 511);
  const unsigned short* base = Cm + row * 1536 + col;
  ushort4 z4 = *(const ushort4*)(base);
  ushort4 r4 = *(const ushort4*)(base + 512);
  ushort4 f4 = *(const ushort4*)(base + 1024);
  float4 p = *(const float4*)(P + i);
  float4 o;
  o.x = bf2f(r4.x) * p.x + bf2f(f4.x) * bf2f(z4.x);
  o.y = bf2f(r4.y) * p.y + bf2f(f4.y) * bf2f(z4.y);
  o.z = bf2f(r4.z) * p.z + bf2f(f4.z) * bf2f(z4.z);
  o.w = bf2f(r4.w) * p.w + bf2f(f4.w) * bf2f(z4.w);
  *(float4*)(out + i) = o;
}

// ---------------------------------------------------------------------------
extern "C" void kernel_launch(void* const* d_in, const int* in_sizes, int n_in,
                              void* d_out, int out_size, void* d_ws, size_t ws_size,
                              hipStream_t stream) {
  const float* P  = (const float*)d_in[0];
  const float* wa = (const float*)d_in[1];
  const float* w1 = (const float*)d_in[2];
  const float* w2 = (const float*)d_in[3];
  const float* w3 = (const float*)d_in[4];
  const float* b1 = (const float*)d_in[5];
  const float* b2 = (const float*)d_in[6];
  const float* b3 = (const float*)d_in[7];
  float* out = (float*)d_out;
  char* ws = (char*)d_ws;
  const size_t MB = 1024 * 1024;

  unsigned short* Pbf  = (unsigned short*)(ws + 0);        // 16 MB, live to end
  unsigned short* PT   = (unsigned short*)(ws + 16 * MB);  // 16 MB, dead after PV
  unsigned short* Qbf  = (unsigned short*)(ws + 32 * MB);  // 16 MB, dead after scores
  unsigned short* Sbuf = (unsigned short*)(ws + 48 * MB);  // 32 MB, dead after PV
  unsigned short* attn = (unsigned short*)(ws + 80 * MB);  // 16 MB
  unsigned short* Wt   = (unsigned short*)(ws + 96 * MB);  // 3 MB  [1536][1024]
  float*          sj   = (float*)(ws + 99 * MB);           // 64 KB
  unsigned short* Cmlp = (unsigned short*)(ws + 16 * MB);  // 48 MB, reuse PT+Qbf+Sbuf

  const long SD = (long)S_LEN * DDIM;        // 1024*512
  const long SS = (long)S_LEN * S_LEN;       // 1024*1024

  prep_rows<<<4096, 256, 0, stream>>>(P, wa, Pbf, Qbf, sj);
  transpose_f2b<<<dim3(8, 16, NBATCH), 256, 0, stream>>>(P, PT, S_LEN, DDIM, SD, SD);
  transpose_f2b<<<dim3(8, 16, 1), 256, 0, stream>>>(w1, Wt,          1024, 512, 0, 0);
  transpose_f2b<<<dim3(8, 16, 1), 256, 0, stream>>>(w2, Wt + SD,     1024, 512, 0, 0);
  transpose_f2b<<<dim3(8, 16, 1), 256, 0, stream>>>(w3, Wt + 2 * SD, 1024, 512, 0, 0);

  // scores: S[b] = Qbf[b] @ Pbf[b]^T + sj[b][col]   (M=N=1024, K=512)
  gemm_nt<1><<<dim3(8, 8, NBATCH), 256, 0, stream>>>(
      Qbf, nullptr, Pbf, Sbuf, sj, nullptr, nullptr,
      1024, 512, 512, 0, SD, SD, SS, S_LEN);
  softmax_rows<<<16384, 256, 0, stream>>>(Sbuf);
  // attn[b] = SA[b] @ PT[b]^T   (M=1024, N=512, K=1024)
  gemm_nt<0><<<dim3(4, 8, NBATCH), 256, 0, stream>>>(
      Sbuf, nullptr, PT, attn, nullptr, nullptr, nullptr,
      512, 1024, 1024, 0, SS, SD, SD, 0);
  // fused MLP: Cmlp[16384][1536] = [Pbf|attn] @ [w1t|w2t|w3t]^T (+bias, act)
  gemm_nt<4><<<dim3(12, 128, 1), 256, 0, stream>>>(
      Pbf, attn, Wt, Cmlp, b1, b2, b3,
      1536, 1024, 512, 512, 0, 0, 0, 0);

  final_out<<<8192, 256, 0, stream>>>(P, Cmlp, out);
}